// Round 1
// baseline (530.044 us; speedup 1.0000x reference)
//
#include <hip/hip_runtime.h>
#include <hip/hip_fp16.h>

// ---------------------------------------------------------------------------
// Phase 1: density regulator  vol[i] = sigmoid(dens[i] - 0.3)  stored as fp16
// ---------------------------------------------------------------------------
__global__ __launch_bounds__(256) void sigmoid_vol_kernel(
    const float* __restrict__ dens, __half* __restrict__ vol, int n)
{
    int i = (blockIdx.x * 256 + threadIdx.x) * 4;
    if (i >= n) return;
    float4 v = *reinterpret_cast<const float4*>(dens + i);
    float s0 = 1.0f / (1.0f + __expf(0.3f - v.x));
    float s1 = 1.0f / (1.0f + __expf(0.3f - v.y));
    float s2 = 1.0f / (1.0f + __expf(0.3f - v.z));
    float s3 = 1.0f / (1.0f + __expf(0.3f - v.w));
    union { __half2 h2[2]; float2 f2; } u;
    u.h2[0] = __floats2half2_rn(s0, s1);
    u.h2[1] = __floats2half2_rn(s2, s3);
    *reinterpret_cast<float2*>(vol + i) = u.f2;
}

// ---------------------------------------------------------------------------
// Corner fetch with map_coordinates(mode="constant", cval=0) semantics:
// each of the 8 corners contributes 0 if its integer index is out of bounds.
// Volume is 256^3, coords[0] strides 65536, coords[1] strides 256, coords[2] 1.
// ---------------------------------------------------------------------------
template <bool PRE>
__device__ __forceinline__ float fetch_corner(
    const __half* __restrict__ vol, const float* __restrict__ dens,
    int x, int y, int z)
{
    if ((unsigned)x < 256u && (unsigned)y < 256u && (unsigned)z < 256u) {
        int idx = (x << 16) | (y << 8) | z;
        if (PRE) {
            return __half2float(vol[idx]);
        } else {
            return 1.0f / (1.0f + __expf(0.3f - dens[idx]));
        }
    }
    return 0.0f;
}

// ---------------------------------------------------------------------------
// Phase 2: one wave (64 lanes) per ray. Lane p handles samples p, p+64, ...
// ---------------------------------------------------------------------------
template <bool PRE>
__global__ __launch_bounds__(256) void drr_kernel(
    const __half* __restrict__ vol,
    const float*  __restrict__ dens,
    const float*  __restrict__ source,
    const float*  __restrict__ target,
    const float*  __restrict__ affine,
    const int*    __restrict__ npts_ptr,
    float*        __restrict__ out,
    int nrays)
{
    const int lane = threadIdx.x & 63;
    const int ray  = blockIdx.x * 4 + (threadIdx.x >> 6);
    if (ray >= nrays) return;
    const int npts = *npts_ptr;

    // --- inverse of the affine (last row assumed [0,0,0,1], as in reference)
    float a00 = affine[0], a01 = affine[1], a02 = affine[2],  b0 = affine[3];
    float a10 = affine[4], a11 = affine[5], a12 = affine[6],  b1 = affine[7];
    float a20 = affine[8], a21 = affine[9], a22 = affine[10], b2 = affine[11];
    float det = a00 * (a11 * a22 - a12 * a21)
              - a01 * (a10 * a22 - a12 * a20)
              + a02 * (a10 * a21 - a11 * a20);
    float rdet = 1.0f / det;
    float i00 =  (a11 * a22 - a12 * a21) * rdet;
    float i01 = -(a01 * a22 - a02 * a21) * rdet;
    float i02 =  (a01 * a12 - a02 * a11) * rdet;
    float i10 = -(a10 * a22 - a12 * a20) * rdet;
    float i11 =  (a00 * a22 - a02 * a20) * rdet;
    float i12 = -(a00 * a12 - a02 * a10) * rdet;
    float i20 =  (a10 * a21 - a11 * a20) * rdet;
    float i21 = -(a00 * a21 - a01 * a20) * rdet;
    float i22 =  (a00 * a11 - a01 * a10) * rdet;
    float it0 = -(i00 * b0 + i01 * b1 + i02 * b2);
    float it1 = -(i10 * b0 + i11 * b1 + i12 * b2);
    float it2 = -(i20 * b0 + i21 * b1 + i22 * b2);

    // --- ray endpoints
    float sx = source[3 * ray + 0], sy = source[3 * ray + 1], sz = source[3 * ray + 2];
    float tx = target[3 * ray + 0], ty = target[3 * ray + 1], tz = target[3 * ray + 2];
    float dwx = tx - sx, dwy = ty - sy, dwz = tz - sz;
    float rl = sqrtf(dwx * dwx + dwy * dwy + dwz * dwz);

    // world -> voxel index space
    float vsx = i00 * sx + i01 * sy + i02 * sz + it0;
    float vsy = i10 * sx + i11 * sy + i12 * sz + it1;
    float vsz = i20 * sx + i21 * sy + i22 * sz + it2;
    float vtx = i00 * tx + i01 * ty + i02 * tz + it0;
    float vty = i10 * tx + i11 * ty + i12 * tz + it1;
    float vtz = i20 * tx + i21 * ty + i22 * tz + it2;
    float vdx = vtx - vsx, vdy = vty - vsy, vdz = vtz - vsz;

    const float step = 1.0f / (float)(npts - 1);
    float acc = 0.0f;

    for (int p = lane; p < npts; p += 64) {
        float al = (float)p * step;
        float x = fmaf(al, vdx, vsx);
        float y = fmaf(al, vdy, vsy);
        float z = fmaf(al, vdz, vsz);

        float fx = floorf(x), fy = floorf(y), fz = floorf(z);
        int ix = (int)fx, iy = (int)fy, iz = (int)fz;
        float wx = x - fx, wy = y - fy, wz = z - fz;

        float c000 = fetch_corner<PRE>(vol, dens, ix,     iy,     iz);
        float c001 = fetch_corner<PRE>(vol, dens, ix,     iy,     iz + 1);
        float c010 = fetch_corner<PRE>(vol, dens, ix,     iy + 1, iz);
        float c011 = fetch_corner<PRE>(vol, dens, ix,     iy + 1, iz + 1);
        float c100 = fetch_corner<PRE>(vol, dens, ix + 1, iy,     iz);
        float c101 = fetch_corner<PRE>(vol, dens, ix + 1, iy,     iz + 1);
        float c110 = fetch_corner<PRE>(vol, dens, ix + 1, iy + 1, iz);
        float c111 = fetch_corner<PRE>(vol, dens, ix + 1, iy + 1, iz + 1);

        float c00 = c000 + wz * (c001 - c000);
        float c01 = c010 + wz * (c011 - c010);
        float c10 = c100 + wz * (c101 - c100);
        float c11 = c110 + wz * (c111 - c110);
        float c0  = c00 + wy * (c01 - c00);
        float c1  = c10 + wy * (c11 - c10);
        acc += c0 + wx * (c1 - c0);
    }

    // wave-64 reduction
    #pragma unroll
    for (int off = 32; off > 0; off >>= 1)
        acc += __shfl_down(acc, off);

    if (lane == 0)
        out[ray] = acc * rl / (float)npts;
}

// ---------------------------------------------------------------------------
extern "C" void kernel_launch(void* const* d_in, const int* in_sizes, int n_in,
                              void* d_out, int out_size, void* d_ws, size_t ws_size,
                              hipStream_t stream)
{
    const float* dens   = (const float*)d_in[0];
    const float* source = (const float*)d_in[1];
    const float* target = (const float*)d_in[2];
    const float* affine = (const float*)d_in[3];
    const int*   npts   = (const int*)d_in[4];
    float* out = (float*)d_out;

    const int nvox  = in_sizes[0];          // 256^3
    const int nrays = in_sizes[1] / 3;      // B*N

    const bool pre = (ws_size >= (size_t)nvox * sizeof(__half));
    const int ray_blocks = (nrays + 3) / 4; // 4 waves per block, 1 ray per wave

    if (pre) {
        __half* vol = (__half*)d_ws;
        int sig_blocks = (nvox / 4 + 255) / 256;
        sigmoid_vol_kernel<<<sig_blocks, 256, 0, stream>>>(dens, vol, nvox);
        drr_kernel<true><<<ray_blocks, 256, 0, stream>>>(
            vol, dens, source, target, affine, npts, out, nrays);
    } else {
        drr_kernel<false><<<ray_blocks, 256, 0, stream>>>(
            nullptr, dens, source, target, affine, npts, out, nrays);
    }
}

// Round 2
// 412.797 us; speedup vs baseline: 1.2840x; 1.2840x over previous
//
#include <hip/hip_runtime.h>
#include <hip/hip_fp16.h>

#define NB 32
#define NBUCKETS (NB * NB)

// ---------------------------------------------------------------------------
// Phase 1: density regulator  vol[i] = sigmoid(dens[i] - 0.3)  stored as fp16
// ---------------------------------------------------------------------------
__global__ __launch_bounds__(256) void sigmoid_vol_kernel(
    const float* __restrict__ dens, __half* __restrict__ vol, int n)
{
    int i = (blockIdx.x * 256 + threadIdx.x) * 4;
    if (i >= n) return;
    float4 v = *reinterpret_cast<const float4*>(dens + i);
    float s0 = 1.0f / (1.0f + __expf(0.3f - v.x));
    float s1 = 1.0f / (1.0f + __expf(0.3f - v.y));
    float s2 = 1.0f / (1.0f + __expf(0.3f - v.z));
    float s3 = 1.0f / (1.0f + __expf(0.3f - v.w));
    union { __half2 h2[2]; float2 f2; } u;
    u.h2[0] = __floats2half2_rn(s0, s1);
    u.h2[1] = __floats2half2_rn(s2, s3);
    *reinterpret_cast<float2*>(vol + i) = u.f2;
}

// ---------------------------------------------------------------------------
// Ray bucketing: Morton-interleaved 32x32 grid over detector (ty, tz)
// ---------------------------------------------------------------------------
__device__ __forceinline__ int ray_bucket(const float* __restrict__ target, int r)
{
    float ty = target[3 * r + 1];
    float tz = target[3 * r + 2];
    int bu = (int)((ty + 10.0f) * (NB / 260.0f));
    int bv = (int)((tz + 10.0f) * (NB / 260.0f));
    bu = min(max(bu, 0), NB - 1);
    bv = min(max(bv, 0), NB - 1);
    int m = 0;
    #pragma unroll
    for (int b = 0; b < 5; ++b)
        m |= (((bu >> b) & 1) << (2 * b)) | (((bv >> b) & 1) << (2 * b + 1));
    return m;
}

__global__ __launch_bounds__(256) void zero_kernel(int* __restrict__ p, int n)
{
    int i = blockIdx.x * 256 + threadIdx.x;
    if (i < n) p[i] = 0;
}

__global__ __launch_bounds__(256) void hist_kernel(
    const float* __restrict__ target, int* __restrict__ hist, int nrays)
{
    int r = blockIdx.x * 256 + threadIdx.x;
    if (r < nrays) atomicAdd(&hist[ray_bucket(target, r)], 1);
}

// single block, NBUCKETS threads: exclusive prefix sum
__global__ __launch_bounds__(NBUCKETS) void scan_kernel(
    const int* __restrict__ hist, int* __restrict__ offs)
{
    __shared__ int a[NBUCKETS], b[NBUCKETS];
    int t = threadIdx.x;
    int h0 = hist[t];
    a[t] = h0;
    __syncthreads();
    int* src = a;
    int* dst = b;
    for (int d = 1; d < NBUCKETS; d <<= 1) {
        dst[t] = src[t] + ((t >= d) ? src[t - d] : 0);
        __syncthreads();
        int* tmp = src; src = dst; dst = tmp;
    }
    offs[t] = src[t] - h0;   // exclusive
}

__global__ __launch_bounds__(256) void scatter_kernel(
    const float* __restrict__ target, const int* __restrict__ offs,
    int* __restrict__ cursor, int* __restrict__ perm, int nrays)
{
    int r = blockIdx.x * 256 + threadIdx.x;
    if (r >= nrays) return;
    int bkt = ray_bucket(target, r);
    int pos = offs[bkt] + atomicAdd(&cursor[bkt], 1);
    perm[pos] = r;
}

// ---------------------------------------------------------------------------
// Trilinear corner fetch with map_coordinates(mode="constant", cval=0)
// ---------------------------------------------------------------------------
__device__ __forceinline__ float fetch_corner(
    const __half* __restrict__ vol, int x, int y, int z)
{
    if ((unsigned)x < 256u && (unsigned)y < 256u && (unsigned)z < 256u)
        return __half2float(vol[(x << 16) | (y << 8) | z]);
    return 0.0f;
}

// ---------------------------------------------------------------------------
// Phase 2: one wave (64 lanes) per ray. Lane p handles samples p, p+64, ...
// perm maps launch slot -> ray id (locality-sorted); may be null.
// ---------------------------------------------------------------------------
__global__ __launch_bounds__(256) void drr_kernel(
    const __half* __restrict__ vol,
    const float*  __restrict__ source,
    const float*  __restrict__ target,
    const float*  __restrict__ affine,
    const int*    __restrict__ npts_ptr,
    const int*    __restrict__ perm,
    float*        __restrict__ out,
    int nrays)
{
    const int lane = threadIdx.x & 63;
    const int slot = blockIdx.x * 4 + (threadIdx.x >> 6);
    if (slot >= nrays) return;
    const int ray = perm ? perm[slot] : slot;
    const int npts = *npts_ptr;

    // --- inverse of the affine (last row assumed [0,0,0,1], as in reference)
    float a00 = affine[0], a01 = affine[1], a02 = affine[2],  b0 = affine[3];
    float a10 = affine[4], a11 = affine[5], a12 = affine[6],  b1 = affine[7];
    float a20 = affine[8], a21 = affine[9], a22 = affine[10], b2 = affine[11];
    float det = a00 * (a11 * a22 - a12 * a21)
              - a01 * (a10 * a22 - a12 * a20)
              + a02 * (a10 * a21 - a11 * a20);
    float rdet = 1.0f / det;
    float i00 =  (a11 * a22 - a12 * a21) * rdet;
    float i01 = -(a01 * a22 - a02 * a21) * rdet;
    float i02 =  (a01 * a12 - a02 * a11) * rdet;
    float i10 = -(a10 * a22 - a12 * a20) * rdet;
    float i11 =  (a00 * a22 - a02 * a20) * rdet;
    float i12 = -(a00 * a12 - a02 * a10) * rdet;
    float i20 =  (a10 * a21 - a11 * a20) * rdet;
    float i21 = -(a00 * a21 - a01 * a20) * rdet;
    float i22 =  (a00 * a11 - a01 * a10) * rdet;
    float it0 = -(i00 * b0 + i01 * b1 + i02 * b2);
    float it1 = -(i10 * b0 + i11 * b1 + i12 * b2);
    float it2 = -(i20 * b0 + i21 * b1 + i22 * b2);

    float sx = source[3 * ray + 0], sy = source[3 * ray + 1], sz = source[3 * ray + 2];
    float tx = target[3 * ray + 0], ty = target[3 * ray + 1], tz = target[3 * ray + 2];
    float dwx = tx - sx, dwy = ty - sy, dwz = tz - sz;
    float rl = sqrtf(dwx * dwx + dwy * dwy + dwz * dwz);

    float vsx = i00 * sx + i01 * sy + i02 * sz + it0;
    float vsy = i10 * sx + i11 * sy + i12 * sz + it1;
    float vsz = i20 * sx + i21 * sy + i22 * sz + it2;
    float vtx = i00 * tx + i01 * ty + i02 * tz + it0;
    float vty = i10 * tx + i11 * ty + i12 * tz + it1;
    float vtz = i20 * tx + i21 * ty + i22 * tz + it2;
    float vdx = vtx - vsx, vdy = vty - vsy, vdz = vtz - vsz;

    const float step = 1.0f / (float)(npts - 1);
    float acc = 0.0f;

    #pragma unroll 2
    for (int p = lane; p < npts; p += 64) {
        float al = (float)p * step;
        float x = fmaf(al, vdx, vsx);
        float y = fmaf(al, vdy, vsy);
        float z = fmaf(al, vdz, vsz);

        float fx = floorf(x), fy = floorf(y), fz = floorf(z);
        int ix = (int)fx, iy = (int)fy, iz = (int)fz;
        float wx = x - fx, wy = y - fy, wz = z - fz;

        float c000 = fetch_corner(vol, ix,     iy,     iz);
        float c001 = fetch_corner(vol, ix,     iy,     iz + 1);
        float c010 = fetch_corner(vol, ix,     iy + 1, iz);
        float c011 = fetch_corner(vol, ix,     iy + 1, iz + 1);
        float c100 = fetch_corner(vol, ix + 1, iy,     iz);
        float c101 = fetch_corner(vol, ix + 1, iy,     iz + 1);
        float c110 = fetch_corner(vol, ix + 1, iy + 1, iz);
        float c111 = fetch_corner(vol, ix + 1, iy + 1, iz + 1);

        float c00 = c000 + wz * (c001 - c000);
        float c01 = c010 + wz * (c011 - c010);
        float c10 = c100 + wz * (c101 - c100);
        float c11 = c110 + wz * (c111 - c110);
        float c0  = c00 + wy * (c01 - c00);
        float c1  = c10 + wy * (c11 - c10);
        acc += c0 + wx * (c1 - c0);
    }

    #pragma unroll
    for (int off = 32; off > 0; off >>= 1)
        acc += __shfl_down(acc, off);

    if (lane == 0)
        out[ray] = acc * rl / (float)npts;
}

// ---------------------------------------------------------------------------
extern "C" void kernel_launch(void* const* d_in, const int* in_sizes, int n_in,
                              void* d_out, int out_size, void* d_ws, size_t ws_size,
                              hipStream_t stream)
{
    const float* dens   = (const float*)d_in[0];
    const float* source = (const float*)d_in[1];
    const float* target = (const float*)d_in[2];
    const float* affine = (const float*)d_in[3];
    const int*   npts   = (const int*)d_in[4];
    float* out = (float*)d_out;

    const int nvox  = in_sizes[0];          // 256^3
    const int nrays = in_sizes[1] / 3;      // B*N

    size_t volBytes = ((size_t)nvox * sizeof(__half) + 255) & ~(size_t)255;
    size_t sortBytes = (size_t)(3 * NBUCKETS + nrays) * sizeof(int);

    const bool pre  = (ws_size >= volBytes);
    const bool srt  = (ws_size >= volBytes + sortBytes);
    const int ray_blocks = (nrays + 3) / 4;

    __half* vol = (__half*)d_ws;
    int* hist   = (int*)((char*)d_ws + volBytes);
    int* offs   = hist + NBUCKETS;
    int* cursor = offs + NBUCKETS;
    int* perm   = cursor + NBUCKETS;

    if (pre) {
        int sig_blocks = (nvox / 4 + 255) / 256;
        sigmoid_vol_kernel<<<sig_blocks, 256, 0, stream>>>(dens, vol, nvox);

        if (srt) {
            zero_kernel<<<(3 * NBUCKETS + 255) / 256, 256, 0, stream>>>(hist, 3 * NBUCKETS);
            hist_kernel<<<(nrays + 255) / 256, 256, 0, stream>>>(target, hist, nrays);
            scan_kernel<<<1, NBUCKETS, 0, stream>>>(hist, offs);
            scatter_kernel<<<(nrays + 255) / 256, 256, 0, stream>>>(target, offs, cursor, perm, nrays);
            drr_kernel<<<ray_blocks, 256, 0, stream>>>(
                vol, source, target, affine, npts, perm, out, nrays);
        } else {
            drr_kernel<<<ray_blocks, 256, 0, stream>>>(
                vol, source, target, affine, npts, nullptr, out, nrays);
        }
    } else {
        // Should not happen for this problem size; correctness fallback:
        // run with fp16 staging skipped is not possible without ws, so just
        // reuse drr with vol==dens reinterpret is invalid — instead do the
        // sigmoid inline via a dedicated slow path kernel. Keep simple: use
        // the first volBytes of out? Not valid either. Fall back to staging
        // into d_ws anyway (ws_size is known to be >= vol for this problem).
        int sig_blocks = (nvox / 4 + 255) / 256;
        sigmoid_vol_kernel<<<sig_blocks, 256, 0, stream>>>(dens, vol, nvox);
        drr_kernel<<<ray_blocks, 256, 0, stream>>>(
            vol, source, target, affine, npts, nullptr, out, nrays);
    }
}

// Round 3
// 262.692 us; speedup vs baseline: 2.0177x; 1.5714x over previous
//
#include <hip/hip_runtime.h>
#include <hip/hip_fp16.h>

#define NB 32
#define NBUCKETS (NB * NB)
#define TD 32

// ---------------------------------------------------------------------------
// Phase 1: fused sigmoid + transpose.
// Input  dens[x][y][z]  (x stride 65536, z stride 1), fp32
// Output vol [z][y][x]  (z stride 65536, x stride 1), fp16
// Rays travel mostly along x, so making x the fastest dim makes the wave's
// gather addresses contiguous.
// One block per (x-tile, z-tile, y): 8*8*256 = 16384 blocks, 256 threads.
// ---------------------------------------------------------------------------
__global__ __launch_bounds__(256) void sigmoid_transpose_kernel(
    const float* __restrict__ dens, __half* __restrict__ vol)
{
    __shared__ float tile[TD][TD + 1];
    int bid = blockIdx.x;
    int xt = (bid & 7) * TD;
    int zt = ((bid >> 3) & 7) * TD;
    int y  = bid >> 6;
    int tz = threadIdx.x & 31;
    int tr = threadIdx.x >> 5;          // 0..7

    #pragma unroll
    for (int i = 0; i < 4; ++i) {
        int xr = tr + 8 * i;            // row within tile
        float v = dens[(size_t)(xt + xr) * 65536 + y * 256 + (zt + tz)];
        tile[xr][tz] = 1.0f / (1.0f + __expf(0.3f - v));
    }
    __syncthreads();
    #pragma unroll
    for (int i = 0; i < 4; ++i) {
        int zr = tr + 8 * i;
        vol[(size_t)(zt + zr) * 65536 + y * 256 + (xt + tz)] =
            __float2half(tile[tz][zr]);
    }
}

// ---------------------------------------------------------------------------
// Ray bucketing: Morton-interleaved 32x32 grid over detector (ty, tz)
// ---------------------------------------------------------------------------
__device__ __forceinline__ int ray_bucket(const float* __restrict__ target, int r)
{
    float ty = target[3 * r + 1];
    float tz = target[3 * r + 2];
    int bu = (int)((ty + 10.0f) * (NB / 260.0f));
    int bv = (int)((tz + 10.0f) * (NB / 260.0f));
    bu = min(max(bu, 0), NB - 1);
    bv = min(max(bv, 0), NB - 1);
    int m = 0;
    #pragma unroll
    for (int b = 0; b < 5; ++b)
        m |= (((bu >> b) & 1) << (2 * b)) | (((bv >> b) & 1) << (2 * b + 1));
    return m;
}

__global__ __launch_bounds__(256) void zero_kernel(int* __restrict__ p, int n)
{
    int i = blockIdx.x * 256 + threadIdx.x;
    if (i < n) p[i] = 0;
}

__global__ __launch_bounds__(256) void hist_kernel(
    const float* __restrict__ target, int* __restrict__ hist, int nrays)
{
    int r = blockIdx.x * 256 + threadIdx.x;
    if (r < nrays) atomicAdd(&hist[ray_bucket(target, r)], 1);
}

__global__ __launch_bounds__(NBUCKETS) void scan_kernel(
    const int* __restrict__ hist, int* __restrict__ offs)
{
    __shared__ int a[NBUCKETS], b[NBUCKETS];
    int t = threadIdx.x;
    int h0 = hist[t];
    a[t] = h0;
    __syncthreads();
    int* src = a;
    int* dst = b;
    for (int d = 1; d < NBUCKETS; d <<= 1) {
        dst[t] = src[t] + ((t >= d) ? src[t - d] : 0);
        __syncthreads();
        int* tmp = src; src = dst; dst = tmp;
    }
    offs[t] = src[t] - h0;   // exclusive
}

__global__ __launch_bounds__(256) void scatter_kernel(
    const float* __restrict__ target, const int* __restrict__ offs,
    int* __restrict__ cursor, int* __restrict__ perm, int nrays)
{
    int r = blockIdx.x * 256 + threadIdx.x;
    if (r >= nrays) return;
    int bkt = ray_bucket(target, r);
    int pos = offs[bkt] + atomicAdd(&cursor[bkt], 1);
    perm[pos] = r;
}

// ---------------------------------------------------------------------------
// Corner fetch in TRANSPOSED layout: addr = (iz<<16) | (iy<<8) | ix
// map_coordinates(mode="constant", cval=0) semantics per corner.
// ---------------------------------------------------------------------------
__device__ __forceinline__ float fetch_corner(
    const __half* __restrict__ vol, int x, int y, int z)
{
    if ((unsigned)x < 256u && (unsigned)y < 256u && (unsigned)z < 256u)
        return __half2float(vol[(z << 16) | (y << 8) | x]);
    return 0.0f;
}

// ---------------------------------------------------------------------------
// Phase 2: one wave per ray; lane p handles samples pstart+p, +64, ...
// Ray clipped to the alpha range where any corner can be in-bounds.
// ---------------------------------------------------------------------------
__global__ __launch_bounds__(256) void drr_kernel(
    const __half* __restrict__ vol,
    const float*  __restrict__ source,
    const float*  __restrict__ target,
    const float*  __restrict__ affine,
    const int*    __restrict__ npts_ptr,
    const int*    __restrict__ perm,
    float*        __restrict__ out,
    int nrays)
{
    const int lane = threadIdx.x & 63;
    const int slot = blockIdx.x * 4 + (threadIdx.x >> 6);
    if (slot >= nrays) return;
    const int ray = perm ? perm[slot] : slot;
    const int npts = *npts_ptr;

    // inverse affine (last row [0,0,0,1])
    float a00 = affine[0], a01 = affine[1], a02 = affine[2],  b0 = affine[3];
    float a10 = affine[4], a11 = affine[5], a12 = affine[6],  b1 = affine[7];
    float a20 = affine[8], a21 = affine[9], a22 = affine[10], b2 = affine[11];
    float det = a00 * (a11 * a22 - a12 * a21)
              - a01 * (a10 * a22 - a12 * a20)
              + a02 * (a10 * a21 - a11 * a20);
    float rdet = 1.0f / det;
    float i00 =  (a11 * a22 - a12 * a21) * rdet;
    float i01 = -(a01 * a22 - a02 * a21) * rdet;
    float i02 =  (a01 * a12 - a02 * a11) * rdet;
    float i10 = -(a10 * a22 - a12 * a20) * rdet;
    float i11 =  (a00 * a22 - a02 * a20) * rdet;
    float i12 = -(a00 * a12 - a02 * a10) * rdet;
    float i20 =  (a10 * a21 - a11 * a20) * rdet;
    float i21 = -(a00 * a21 - a01 * a20) * rdet;
    float i22 =  (a00 * a11 - a01 * a10) * rdet;
    float it0 = -(i00 * b0 + i01 * b1 + i02 * b2);
    float it1 = -(i10 * b0 + i11 * b1 + i12 * b2);
    float it2 = -(i20 * b0 + i21 * b1 + i22 * b2);

    float sx = source[3 * ray + 0], sy = source[3 * ray + 1], sz = source[3 * ray + 2];
    float tx = target[3 * ray + 0], ty = target[3 * ray + 1], tz = target[3 * ray + 2];
    float dwx = tx - sx, dwy = ty - sy, dwz = tz - sz;
    float rl = sqrtf(dwx * dwx + dwy * dwy + dwz * dwz);

    float vsx = i00 * sx + i01 * sy + i02 * sz + it0;
    float vsy = i10 * sx + i11 * sy + i12 * sz + it1;
    float vsz = i20 * sx + i21 * sy + i22 * sz + it2;
    float vtx = i00 * tx + i01 * ty + i02 * tz + it0;
    float vty = i10 * tx + i11 * ty + i12 * tz + it1;
    float vtz = i20 * tx + i21 * ty + i22 * tz + it2;
    float vdx = vtx - vsx, vdy = vty - vsy, vdz = vtz - vsz;

    // clip to alpha range where a sample can touch an in-bounds corner:
    // coordinate must lie in (-1, 256)
    float lo = 0.0f, hi = 1.0f;
    {
        float s[3] = {vsx, vsy, vsz};
        float d[3] = {vdx, vdy, vdz};
        #pragma unroll
        for (int k = 0; k < 3; ++k) {
            if (fabsf(d[k]) > 1e-8f) {
                float a = (-1.0f - s[k]) / d[k];
                float b = (256.0f - s[k]) / d[k];
                lo = fmaxf(lo, fminf(a, b));
                hi = fminf(hi, fmaxf(a, b));
            } else if (s[k] <= -1.0f || s[k] >= 256.0f) {
                lo = 1.0f; hi = 0.0f;
            }
        }
    }
    const float stepN = (float)(npts > 1 ? npts - 1 : 1);
    int pstart = max(0, (int)floorf(lo * stepN) - 1);
    int pend   = min(npts - 1, (int)ceilf(hi * stepN) + 1);

    const float step = 1.0f / stepN;
    float acc = 0.0f;

    #pragma unroll 4
    for (int p = pstart + lane; p <= pend; p += 64) {
        float al = (float)p * step;
        float x = fmaf(al, vdx, vsx);
        float y = fmaf(al, vdy, vsy);
        float z = fmaf(al, vdz, vsz);

        float fx = floorf(x), fy = floorf(y), fz = floorf(z);
        int ix = (int)fx, iy = (int)fy, iz = (int)fz;
        float wx = x - fx, wy = y - fy, wz = z - fz;

        float c000 = fetch_corner(vol, ix,     iy,     iz);
        float c100 = fetch_corner(vol, ix + 1, iy,     iz);
        float c010 = fetch_corner(vol, ix,     iy + 1, iz);
        float c110 = fetch_corner(vol, ix + 1, iy + 1, iz);
        float c001 = fetch_corner(vol, ix,     iy,     iz + 1);
        float c101 = fetch_corner(vol, ix + 1, iy,     iz + 1);
        float c011 = fetch_corner(vol, ix,     iy + 1, iz + 1);
        float c111 = fetch_corner(vol, ix + 1, iy + 1, iz + 1);

        float c00 = c000 + wz * (c001 - c000);
        float c01 = c010 + wz * (c011 - c010);
        float c10 = c100 + wz * (c101 - c100);
        float c11 = c110 + wz * (c111 - c110);
        float c0  = c00 + wy * (c01 - c00);
        float c1  = c10 + wy * (c11 - c10);
        acc += c0 + wx * (c1 - c0);
    }

    #pragma unroll
    for (int off = 32; off > 0; off >>= 1)
        acc += __shfl_down(acc, off);

    if (lane == 0)
        out[ray] = acc * rl / (float)npts;
}

// ---------------------------------------------------------------------------
extern "C" void kernel_launch(void* const* d_in, const int* in_sizes, int n_in,
                              void* d_out, int out_size, void* d_ws, size_t ws_size,
                              hipStream_t stream)
{
    const float* dens   = (const float*)d_in[0];
    const float* source = (const float*)d_in[1];
    const float* target = (const float*)d_in[2];
    const float* affine = (const float*)d_in[3];
    const int*   npts   = (const int*)d_in[4];
    float* out = (float*)d_out;

    const int nvox  = in_sizes[0];          // 256^3
    const int nrays = in_sizes[1] / 3;      // B*N

    size_t volBytes  = ((size_t)nvox * sizeof(__half) + 255) & ~(size_t)255;
    size_t sortBytes = (size_t)(3 * NBUCKETS + nrays) * sizeof(int);

    const bool srt = (ws_size >= volBytes + sortBytes);
    const int ray_blocks = (nrays + 3) / 4;

    __half* vol = (__half*)d_ws;
    int* hist   = (int*)((char*)d_ws + volBytes);
    int* offs   = hist + NBUCKETS;
    int* cursor = offs + NBUCKETS;
    int* perm   = cursor + NBUCKETS;

    sigmoid_transpose_kernel<<<16384, 256, 0, stream>>>(dens, vol);

    if (srt) {
        zero_kernel<<<(3 * NBUCKETS + 255) / 256, 256, 0, stream>>>(hist, 3 * NBUCKETS);
        hist_kernel<<<(nrays + 255) / 256, 256, 0, stream>>>(target, hist, nrays);
        scan_kernel<<<1, NBUCKETS, 0, stream>>>(hist, offs);
        scatter_kernel<<<(nrays + 255) / 256, 256, 0, stream>>>(target, offs, cursor, perm, nrays);
        drr_kernel<<<ray_blocks, 256, 0, stream>>>(
            vol, source, target, affine, npts, perm, out, nrays);
    } else {
        drr_kernel<<<ray_blocks, 256, 0, stream>>>(
            vol, source, target, affine, npts, nullptr, out, nrays);
    }
}

// Round 4
// 210.874 us; speedup vs baseline: 2.5136x; 1.2457x over previous
//
#include <hip/hip_runtime.h>
#include <hip/hip_fp16.h>

#define NB 32
#define NBUCKETS (NB * NB)

__device__ __forceinline__ float sigm(float v)
{
    return 1.0f / (1.0f + __expf(0.3f - v));
}

// ---------------------------------------------------------------------------
// Phase 1a (packed path): sigmoid + transpose + y-pair pack.
// Input  dens[x][y][z] fp32 (z fastest). Output P[z][y][x] uint (x fastest),
// where P = half2( sig(v[z][y][x]), sig(v[z][y+1][x]) ), y+1==256 -> 0.
// Block id: y in LOW bits so consecutive blocks share the y+1 plane in L2.
// ---------------------------------------------------------------------------
__global__ __launch_bounds__(256) void pack_kernel(
    const float* __restrict__ dens, unsigned int* __restrict__ P)
{
    __shared__ float t0[32][33];
    __shared__ float t1[32][33];
    int bid = blockIdx.x;
    int y  = bid & 255;
    int xt = ((bid >> 8) & 7) * 32;
    int zt = (bid >> 11) * 32;
    int tz = threadIdx.x & 31;
    int tr = threadIdx.x >> 5;              // 0..7

    bool has_y1 = (y < 255);
    #pragma unroll
    for (int i = 0; i < 4; ++i) {
        int xr = tr + 8 * i;
        size_t base = (size_t)(xt + xr) * 65536 + (size_t)y * 256 + (zt + tz);
        t0[xr][tz] = sigm(dens[base]);
        t1[xr][tz] = has_y1 ? sigm(dens[base + 256]) : 0.0f;
    }
    __syncthreads();
    #pragma unroll
    for (int i = 0; i < 4; ++i) {
        int zr = tr + 8 * i;
        __half2 h = __floats2half2_rn(t0[tz][zr], t1[tz][zr]);
        P[((zt + zr) << 16) | (y << 8) | (xt + tz)] =
            *reinterpret_cast<unsigned int*>(&h);
    }
}

// ---------------------------------------------------------------------------
// Phase 1b (fallback path): sigmoid + transpose to fp16, x fastest.
// ---------------------------------------------------------------------------
__global__ __launch_bounds__(256) void sigmoid_transpose_kernel(
    const float* __restrict__ dens, __half* __restrict__ vol)
{
    __shared__ float tile[32][33];
    int bid = blockIdx.x;
    int xt = (bid & 7) * 32;
    int zt = ((bid >> 3) & 7) * 32;
    int y  = bid >> 6;
    int tz = threadIdx.x & 31;
    int tr = threadIdx.x >> 5;

    #pragma unroll
    for (int i = 0; i < 4; ++i) {
        int xr = tr + 8 * i;
        tile[xr][tz] = sigm(dens[(size_t)(xt + xr) * 65536 + y * 256 + (zt + tz)]);
    }
    __syncthreads();
    #pragma unroll
    for (int i = 0; i < 4; ++i) {
        int zr = tr + 8 * i;
        vol[((zt + zr) << 16) | (y << 8) | (xt + tz)] = __float2half(tile[tz][zr]);
    }
}

// ---------------------------------------------------------------------------
// Ray bucketing: Morton-interleaved 32x32 grid over detector (ty, tz)
// ---------------------------------------------------------------------------
__device__ __forceinline__ int ray_bucket(const float* __restrict__ target, int r)
{
    float ty = target[3 * r + 1];
    float tz = target[3 * r + 2];
    int bu = (int)((ty + 10.0f) * (NB / 260.0f));
    int bv = (int)((tz + 10.0f) * (NB / 260.0f));
    bu = min(max(bu, 0), NB - 1);
    bv = min(max(bv, 0), NB - 1);
    int m = 0;
    #pragma unroll
    for (int b = 0; b < 5; ++b)
        m |= (((bu >> b) & 1) << (2 * b)) | (((bv >> b) & 1) << (2 * b + 1));
    return m;
}

__global__ __launch_bounds__(256) void zero_kernel(int* __restrict__ p, int n)
{
    int i = blockIdx.x * 256 + threadIdx.x;
    if (i < n) p[i] = 0;
}

__global__ __launch_bounds__(256) void hist_kernel(
    const float* __restrict__ target, int* __restrict__ hist, int nrays)
{
    int r = blockIdx.x * 256 + threadIdx.x;
    if (r < nrays) atomicAdd(&hist[ray_bucket(target, r)], 1);
}

__global__ __launch_bounds__(NBUCKETS) void scan_kernel(
    const int* __restrict__ hist, int* __restrict__ offs)
{
    __shared__ int a[NBUCKETS], b[NBUCKETS];
    int t = threadIdx.x;
    int h0 = hist[t];
    a[t] = h0;
    __syncthreads();
    int* src = a;
    int* dst = b;
    for (int d = 1; d < NBUCKETS; d <<= 1) {
        dst[t] = src[t] + ((t >= d) ? src[t - d] : 0);
        __syncthreads();
        int* tmp = src; src = dst; dst = tmp;
    }
    offs[t] = src[t] - h0;   // exclusive
}

__global__ __launch_bounds__(256) void scatter_kernel(
    const float* __restrict__ target, const int* __restrict__ offs,
    int* __restrict__ cursor, int* __restrict__ perm, int nrays)
{
    int r = blockIdx.x * 256 + threadIdx.x;
    if (r >= nrays) return;
    int bkt = ray_bucket(target, r);
    int pos = offs[bkt] + atomicAdd(&cursor[bkt], 1);
    perm[pos] = r;
}

// ---------------------------------------------------------------------------
// Checked packed fetch: returns (corner at y, corner at y+1); zeros per
// map_coordinates(mode="constant") semantics.
// ---------------------------------------------------------------------------
__device__ __forceinline__ float2 fetchP(
    const unsigned int* __restrict__ P, int x, int y, int z)
{
    if ((unsigned)x < 256u && (unsigned)z < 256u) {
        if ((unsigned)y < 256u) {
            unsigned int v = P[(z << 16) | (y << 8) | x];
            __half2 h = *reinterpret_cast<__half2*>(&v);
            return make_float2(__low2float(h), __high2float(h));
        }
        if (y == -1) {
            unsigned int v = P[(z << 16) | x];
            __half2 h = *reinterpret_cast<__half2*>(&v);
            return make_float2(0.0f, __low2float(h));
        }
    }
    return make_float2(0.0f, 0.0f);
}

__device__ __forceinline__ float fetch_half(
    const __half* __restrict__ vol, int x, int y, int z)
{
    if ((unsigned)x < 256u && (unsigned)y < 256u && (unsigned)z < 256u)
        return __half2float(vol[(z << 16) | (y << 8) | x]);
    return 0.0f;
}

// ---------------------------------------------------------------------------
// Phase 2: one wave per ray, clipped; PACKED selects 4-dword-gather path.
// ---------------------------------------------------------------------------
template <bool PACKED>
__global__ __launch_bounds__(256) void drr_kernel(
    const void*   __restrict__ volp,
    const float*  __restrict__ source,
    const float*  __restrict__ target,
    const float*  __restrict__ affine,
    const int*    __restrict__ npts_ptr,
    const int*    __restrict__ perm,
    float*        __restrict__ out,
    int nrays)
{
    const int lane = threadIdx.x & 63;
    const int slot = blockIdx.x * 4 + (threadIdx.x >> 6);
    if (slot >= nrays) return;
    const int ray = perm ? perm[slot] : slot;
    const int npts = *npts_ptr;

    // inverse affine (last row [0,0,0,1])
    float a00 = affine[0], a01 = affine[1], a02 = affine[2],  b0 = affine[3];
    float a10 = affine[4], a11 = affine[5], a12 = affine[6],  b1 = affine[7];
    float a20 = affine[8], a21 = affine[9], a22 = affine[10], b2 = affine[11];
    float det = a00 * (a11 * a22 - a12 * a21)
              - a01 * (a10 * a22 - a12 * a20)
              + a02 * (a10 * a21 - a11 * a20);
    float rdet = 1.0f / det;
    float i00 =  (a11 * a22 - a12 * a21) * rdet;
    float i01 = -(a01 * a22 - a02 * a21) * rdet;
    float i02 =  (a01 * a12 - a02 * a11) * rdet;
    float i10 = -(a10 * a22 - a12 * a20) * rdet;
    float i11 =  (a00 * a22 - a02 * a20) * rdet;
    float i12 = -(a00 * a12 - a02 * a10) * rdet;
    float i20 =  (a10 * a21 - a11 * a20) * rdet;
    float i21 = -(a00 * a21 - a01 * a20) * rdet;
    float i22 =  (a00 * a11 - a01 * a10) * rdet;
    float it0 = -(i00 * b0 + i01 * b1 + i02 * b2);
    float it1 = -(i10 * b0 + i11 * b1 + i12 * b2);
    float it2 = -(i20 * b0 + i21 * b1 + i22 * b2);

    float sx = source[3 * ray + 0], sy = source[3 * ray + 1], sz = source[3 * ray + 2];
    float tx = target[3 * ray + 0], ty = target[3 * ray + 1], tz = target[3 * ray + 2];
    float dwx = tx - sx, dwy = ty - sy, dwz = tz - sz;
    float rl = sqrtf(dwx * dwx + dwy * dwy + dwz * dwz);

    float vsx = i00 * sx + i01 * sy + i02 * sz + it0;
    float vsy = i10 * sx + i11 * sy + i12 * sz + it1;
    float vsz = i20 * sx + i21 * sy + i22 * sz + it2;
    float vtx = i00 * tx + i01 * ty + i02 * tz + it0;
    float vty = i10 * tx + i11 * ty + i12 * tz + it1;
    float vtz = i20 * tx + i21 * ty + i22 * tz + it2;
    float vdx = vtx - vsx, vdy = vty - vsy, vdz = vtz - vsz;

    // clip to alpha range where a sample can touch an in-bounds corner
    float lo = 0.0f, hi = 1.0f;
    {
        float s3v[3] = {vsx, vsy, vsz};
        float d3v[3] = {vdx, vdy, vdz};
        #pragma unroll
        for (int k = 0; k < 3; ++k) {
            if (fabsf(d3v[k]) > 1e-8f) {
                float a = (-1.0f - s3v[k]) / d3v[k];
                float b = (256.0f - s3v[k]) / d3v[k];
                lo = fmaxf(lo, fminf(a, b));
                hi = fminf(hi, fmaxf(a, b));
            } else if (s3v[k] <= -1.0f || s3v[k] >= 256.0f) {
                lo = 1.0f; hi = 0.0f;
            }
        }
    }
    const float stepN = (float)(npts > 1 ? npts - 1 : 1);
    int pstart = max(0, (int)floorf(lo * stepN) - 1);
    int pend   = min(npts - 1, (int)ceilf(hi * stepN) + 1);

    const float step = 1.0f / stepN;
    float acc = 0.0f;

    const unsigned int* P  = (const unsigned int*)volp;
    const __half*       Vh = (const __half*)volp;

    #pragma unroll 4
    for (int p = pstart + lane; p <= pend; p += 64) {
        float al = (float)p * step;
        float x = fmaf(al, vdx, vsx);
        float y = fmaf(al, vdy, vsy);
        float z = fmaf(al, vdz, vsz);

        float fx = floorf(x), fy = floorf(y), fz = floorf(z);
        int ix = (int)fx, iy = (int)fy, iz = (int)fz;
        float wx = x - fx, wy = y - fy, wz = z - fz;

        if (PACKED) {
            float2 p00, p01, p10, p11;   // (y, y+1) pairs at (x|x+1, z|z+1)
            bool interior = ((unsigned)ix < 255u) & ((unsigned)iy < 256u) &
                            ((unsigned)iz < 255u);
            if (interior) {
                int idx = (iz << 16) | (iy << 8) | ix;
                unsigned int v00 = P[idx];
                unsigned int v01 = P[idx + 1];
                unsigned int v10 = P[idx + 65536];
                unsigned int v11 = P[idx + 65537];
                __half2 h00 = *reinterpret_cast<__half2*>(&v00);
                __half2 h01 = *reinterpret_cast<__half2*>(&v01);
                __half2 h10 = *reinterpret_cast<__half2*>(&v10);
                __half2 h11 = *reinterpret_cast<__half2*>(&v11);
                p00 = make_float2(__low2float(h00), __high2float(h00));
                p01 = make_float2(__low2float(h01), __high2float(h01));
                p10 = make_float2(__low2float(h10), __high2float(h10));
                p11 = make_float2(__low2float(h11), __high2float(h11));
            } else {
                p00 = fetchP(P, ix,     iy, iz);
                p01 = fetchP(P, ix + 1, iy, iz);
                p10 = fetchP(P, ix,     iy, iz + 1);
                p11 = fetchP(P, ix + 1, iy, iz + 1);
            }
            float c00 = p00.x + wy * (p00.y - p00.x);   // (x,   z)
            float c10 = p01.x + wy * (p01.y - p01.x);   // (x+1, z)
            float c01 = p10.x + wy * (p10.y - p10.x);   // (x,   z+1)
            float c11 = p11.x + wy * (p11.y - p11.x);   // (x+1, z+1)
            float c0  = c00 + wz * (c01 - c00);
            float c1  = c10 + wz * (c11 - c10);
            acc += c0 + wx * (c1 - c0);
        } else {
            float c000 = fetch_half(Vh, ix,     iy,     iz);
            float c100 = fetch_half(Vh, ix + 1, iy,     iz);
            float c010 = fetch_half(Vh, ix,     iy + 1, iz);
            float c110 = fetch_half(Vh, ix + 1, iy + 1, iz);
            float c001 = fetch_half(Vh, ix,     iy,     iz + 1);
            float c101 = fetch_half(Vh, ix + 1, iy,     iz + 1);
            float c011 = fetch_half(Vh, ix,     iy + 1, iz + 1);
            float c111 = fetch_half(Vh, ix + 1, iy + 1, iz + 1);
            float c00 = c000 + wz * (c001 - c000);
            float c01 = c010 + wz * (c011 - c010);
            float c10 = c100 + wz * (c101 - c100);
            float c11 = c110 + wz * (c111 - c110);
            float c0  = c00 + wy * (c01 - c00);
            float c1  = c10 + wy * (c11 - c10);
            acc += c0 + wx * (c1 - c0);
        }
    }

    #pragma unroll
    for (int off = 32; off > 0; off >>= 1)
        acc += __shfl_down(acc, off);

    if (lane == 0)
        out[ray] = acc * rl / (float)npts;
}

// ---------------------------------------------------------------------------
extern "C" void kernel_launch(void* const* d_in, const int* in_sizes, int n_in,
                              void* d_out, int out_size, void* d_ws, size_t ws_size,
                              hipStream_t stream)
{
    const float* dens   = (const float*)d_in[0];
    const float* source = (const float*)d_in[1];
    const float* target = (const float*)d_in[2];
    const float* affine = (const float*)d_in[3];
    const int*   npts   = (const int*)d_in[4];
    float* out = (float*)d_out;

    const int nvox  = in_sizes[0];          // 256^3
    const int nrays = in_sizes[1] / 3;      // B*N

    size_t packBytes = ((size_t)nvox * 4 + 255) & ~(size_t)255;
    size_t halfBytes = ((size_t)nvox * 2 + 255) & ~(size_t)255;
    size_t sortBytes = (size_t)(3 * NBUCKETS + nrays) * sizeof(int);

    const int ray_blocks = (nrays + 3) / 4;

    const bool packed = (ws_size >= packBytes + sortBytes);
    size_t volBytes = packed ? packBytes : halfBytes;

    int* hist   = (int*)((char*)d_ws + volBytes);
    int* offs   = hist + NBUCKETS;
    int* cursor = offs + NBUCKETS;
    int* perm   = cursor + NBUCKETS;
    const bool srt = (ws_size >= volBytes + sortBytes);
    int* permArg = srt ? perm : nullptr;

    if (srt) {
        zero_kernel<<<(3 * NBUCKETS + 255) / 256, 256, 0, stream>>>(hist, 3 * NBUCKETS);
        hist_kernel<<<(nrays + 255) / 256, 256, 0, stream>>>(target, hist, nrays);
        scan_kernel<<<1, NBUCKETS, 0, stream>>>(hist, offs);
        scatter_kernel<<<(nrays + 255) / 256, 256, 0, stream>>>(target, offs, cursor, perm, nrays);
    }

    if (packed) {
        unsigned int* P = (unsigned int*)d_ws;
        pack_kernel<<<16384, 256, 0, stream>>>(dens, P);
        drr_kernel<true><<<ray_blocks, 256, 0, stream>>>(
            P, source, target, affine, npts, permArg, out, nrays);
    } else {
        __half* vol = (__half*)d_ws;
        sigmoid_transpose_kernel<<<16384, 256, 0, stream>>>(dens, vol);
        drr_kernel<false><<<ray_blocks, 256, 0, stream>>>(
            vol, source, target, affine, npts, permArg, out, nrays);
    }
}

// Round 5
// 195.373 us; speedup vs baseline: 2.7130x; 1.0793x over previous
//
#include <hip/hip_runtime.h>
#include <hip/hip_fp16.h>

#define NB 32
#define NBUCKETS (NB * NB)

typedef unsigned int uint2v __attribute__((ext_vector_type(2)));

__device__ __forceinline__ float sigm(float v)
{
    return 1.0f / (1.0f + __expf(0.3f - v));
}

__device__ __forceinline__ float2 unpack_h2(unsigned int w)
{
    __half2 h = *reinterpret_cast<__half2*>(&w);
    return make_float2(__low2float(h), __high2float(h));
}

// ---------------------------------------------------------------------------
// Phase 1a (packed path): sigmoid + transpose + y-pair pack, with y-carry.
// Input  dens[x][y][z] fp32 (z fastest). Output P[z][y][x] uint (x fastest),
// P = half2( sig(v[z][y][x]), sig(v[z][y+1][x]) ), y+1==256 -> 0.
// Each block handles one (32x,32z) tile for 8 consecutive y planes, carrying
// the y+1 plane's transposed sigmoid in registers: 9 plane reads / 8 outputs.
// Grid: 8 x-tiles * 8 z-tiles * 32 y-groups = 2048 blocks.
// ---------------------------------------------------------------------------
__global__ __launch_bounds__(256) void pack_kernel(
    const float* __restrict__ dens, unsigned int* __restrict__ P)
{
    __shared__ float tile[32][33];
    int bid = blockIdx.x;
    int y0 = (bid & 31) * 8;
    int xt = ((bid >> 5) & 7) * 32;
    int zt = (bid >> 8) * 32;
    int tz = threadIdx.x & 31;
    int tr = threadIdx.x >> 5;              // 0..7

    float prev[4];                           // plane y+1, transposed arrangement
    int ytop = y0 + 8;
    if (ytop < 256) {
        #pragma unroll
        for (int i = 0; i < 4; ++i) {
            int xr = tr + 8 * i;
            tile[xr][tz] = sigm(dens[(size_t)(xt + xr) * 65536 +
                                     (size_t)ytop * 256 + (zt + tz)]);
        }
        __syncthreads();
        #pragma unroll
        for (int i = 0; i < 4; ++i)
            prev[i] = tile[tz][tr + 8 * i];
        __syncthreads();
    } else {
        #pragma unroll
        for (int i = 0; i < 4; ++i) prev[i] = 0.0f;
    }

    for (int yy = 7; yy >= 0; --yy) {
        int y = y0 + yy;
        #pragma unroll
        for (int i = 0; i < 4; ++i) {
            int xr = tr + 8 * i;
            tile[xr][tz] = sigm(dens[(size_t)(xt + xr) * 65536 +
                                     (size_t)y * 256 + (zt + tz)]);
        }
        __syncthreads();
        #pragma unroll
        for (int i = 0; i < 4; ++i) {
            int zr = tr + 8 * i;
            float cur = tile[tz][zr];
            __half2 h = __floats2half2_rn(cur, prev[i]);
            P[((zt + zr) << 16) | (y << 8) | (xt + tz)] =
                *reinterpret_cast<unsigned int*>(&h);
            prev[i] = cur;
        }
        __syncthreads();
    }
}

// ---------------------------------------------------------------------------
// Phase 1b (fallback path): sigmoid + transpose to fp16, x fastest.
// ---------------------------------------------------------------------------
__global__ __launch_bounds__(256) void sigmoid_transpose_kernel(
    const float* __restrict__ dens, __half* __restrict__ vol)
{
    __shared__ float tile[32][33];
    int bid = blockIdx.x;
    int xt = (bid & 7) * 32;
    int zt = ((bid >> 3) & 7) * 32;
    int y  = bid >> 6;
    int tz = threadIdx.x & 31;
    int tr = threadIdx.x >> 5;

    #pragma unroll
    for (int i = 0; i < 4; ++i) {
        int xr = tr + 8 * i;
        tile[xr][tz] = sigm(dens[(size_t)(xt + xr) * 65536 + y * 256 + (zt + tz)]);
    }
    __syncthreads();
    #pragma unroll
    for (int i = 0; i < 4; ++i) {
        int zr = tr + 8 * i;
        vol[((zt + zr) << 16) | (y << 8) | (xt + tz)] = __float2half(tile[tz][zr]);
    }
}

// ---------------------------------------------------------------------------
// Ray bucketing: Morton-interleaved 32x32 grid over detector (ty, tz)
// ---------------------------------------------------------------------------
__device__ __forceinline__ int ray_bucket(const float* __restrict__ target, int r)
{
    float ty = target[3 * r + 1];
    float tz = target[3 * r + 2];
    int bu = (int)((ty + 10.0f) * (NB / 260.0f));
    int bv = (int)((tz + 10.0f) * (NB / 260.0f));
    bu = min(max(bu, 0), NB - 1);
    bv = min(max(bv, 0), NB - 1);
    int m = 0;
    #pragma unroll
    for (int b = 0; b < 5; ++b)
        m |= (((bu >> b) & 1) << (2 * b)) | (((bv >> b) & 1) << (2 * b + 1));
    return m;
}

__global__ __launch_bounds__(256) void zero_kernel(int* __restrict__ p, int n)
{
    int i = blockIdx.x * 256 + threadIdx.x;
    if (i < n) p[i] = 0;
}

__global__ __launch_bounds__(256) void hist_kernel(
    const float* __restrict__ target, int* __restrict__ hist, int nrays)
{
    int r = blockIdx.x * 256 + threadIdx.x;
    if (r < nrays) atomicAdd(&hist[ray_bucket(target, r)], 1);
}

__global__ __launch_bounds__(NBUCKETS) void scan_kernel(
    const int* __restrict__ hist, int* __restrict__ offs)
{
    __shared__ int a[NBUCKETS], b[NBUCKETS];
    int t = threadIdx.x;
    int h0 = hist[t];
    a[t] = h0;
    __syncthreads();
    int* src = a;
    int* dst = b;
    for (int d = 1; d < NBUCKETS; d <<= 1) {
        dst[t] = src[t] + ((t >= d) ? src[t - d] : 0);
        __syncthreads();
        int* tmp = src; src = dst; dst = tmp;
    }
    offs[t] = src[t] - h0;   // exclusive
}

__global__ __launch_bounds__(256) void scatter_kernel(
    const float* __restrict__ target, const int* __restrict__ offs,
    int* __restrict__ cursor, int* __restrict__ perm, int nrays)
{
    int r = blockIdx.x * 256 + threadIdx.x;
    if (r >= nrays) return;
    int bkt = ray_bucket(target, r);
    int pos = offs[bkt] + atomicAdd(&cursor[bkt], 1);
    perm[pos] = r;
}

// ---------------------------------------------------------------------------
// Checked packed fetch (boundary path)
// ---------------------------------------------------------------------------
__device__ __forceinline__ float2 fetchP(
    const unsigned int* __restrict__ P, int x, int y, int z)
{
    if ((unsigned)x < 256u && (unsigned)z < 256u) {
        if ((unsigned)y < 256u)
            return unpack_h2(P[(z << 16) | (y << 8) | x]);
        if (y == -1) {
            float2 v = unpack_h2(P[(z << 16) | x]);
            return make_float2(0.0f, v.x);
        }
    }
    return make_float2(0.0f, 0.0f);
}

__device__ __forceinline__ float fetch_half(
    const __half* __restrict__ vol, int x, int y, int z)
{
    if ((unsigned)x < 256u && (unsigned)y < 256u && (unsigned)z < 256u)
        return __half2float(vol[(z << 16) | (y << 8) | x]);
    return 0.0f;
}

// ---------------------------------------------------------------------------
// Phase 2: one wave per ray, clipped; PACKED: 2 x dwordx2 gathers per sample.
// ---------------------------------------------------------------------------
template <bool PACKED>
__global__ __launch_bounds__(256) void drr_kernel(
    const void*   __restrict__ volp,
    const float*  __restrict__ source,
    const float*  __restrict__ target,
    const float*  __restrict__ affine,
    const int*    __restrict__ npts_ptr,
    const int*    __restrict__ perm,
    float*        __restrict__ out,
    int nrays)
{
    const int lane = threadIdx.x & 63;
    const int slot = blockIdx.x * 4 + (threadIdx.x >> 6);
    if (slot >= nrays) return;
    const int ray = perm ? perm[slot] : slot;
    const int npts = *npts_ptr;

    // inverse affine (last row [0,0,0,1])
    float a00 = affine[0], a01 = affine[1], a02 = affine[2],  b0 = affine[3];
    float a10 = affine[4], a11 = affine[5], a12 = affine[6],  b1 = affine[7];
    float a20 = affine[8], a21 = affine[9], a22 = affine[10], b2 = affine[11];
    float det = a00 * (a11 * a22 - a12 * a21)
              - a01 * (a10 * a22 - a12 * a20)
              + a02 * (a10 * a21 - a11 * a20);
    float rdet = 1.0f / det;
    float i00 =  (a11 * a22 - a12 * a21) * rdet;
    float i01 = -(a01 * a22 - a02 * a21) * rdet;
    float i02 =  (a01 * a12 - a02 * a11) * rdet;
    float i10 = -(a10 * a22 - a12 * a20) * rdet;
    float i11 =  (a00 * a22 - a02 * a20) * rdet;
    float i12 = -(a00 * a12 - a02 * a10) * rdet;
    float i20 =  (a10 * a21 - a11 * a20) * rdet;
    float i21 = -(a00 * a21 - a01 * a20) * rdet;
    float i22 =  (a00 * a11 - a01 * a10) * rdet;
    float it0 = -(i00 * b0 + i01 * b1 + i02 * b2);
    float it1 = -(i10 * b0 + i11 * b1 + i12 * b2);
    float it2 = -(i20 * b0 + i21 * b1 + i22 * b2);

    float sx = source[3 * ray + 0], sy = source[3 * ray + 1], sz = source[3 * ray + 2];
    float tx = target[3 * ray + 0], ty = target[3 * ray + 1], tz = target[3 * ray + 2];
    float dwx = tx - sx, dwy = ty - sy, dwz = tz - sz;
    float rl = sqrtf(dwx * dwx + dwy * dwy + dwz * dwz);

    float vsx = i00 * sx + i01 * sy + i02 * sz + it0;
    float vsy = i10 * sx + i11 * sy + i12 * sz + it1;
    float vsz = i20 * sx + i21 * sy + i22 * sz + it2;
    float vtx = i00 * tx + i01 * ty + i02 * tz + it0;
    float vty = i10 * tx + i11 * ty + i12 * tz + it1;
    float vtz = i20 * tx + i21 * ty + i22 * tz + it2;
    float vdx = vtx - vsx, vdy = vty - vsy, vdz = vtz - vsz;

    // clip to alpha range where a sample can touch an in-bounds corner
    float lo = 0.0f, hi = 1.0f;
    {
        float s3v[3] = {vsx, vsy, vsz};
        float d3v[3] = {vdx, vdy, vdz};
        #pragma unroll
        for (int k = 0; k < 3; ++k) {
            if (fabsf(d3v[k]) > 1e-8f) {
                float a = (-1.0f - s3v[k]) / d3v[k];
                float b = (256.0f - s3v[k]) / d3v[k];
                lo = fmaxf(lo, fminf(a, b));
                hi = fminf(hi, fmaxf(a, b));
            } else if (s3v[k] <= -1.0f || s3v[k] >= 256.0f) {
                lo = 1.0f; hi = 0.0f;
            }
        }
    }
    const float stepN = (float)(npts > 1 ? npts - 1 : 1);
    int pstart = max(0, (int)floorf(lo * stepN) - 1);
    int pend   = min(npts - 1, (int)ceilf(hi * stepN) + 1);

    const float step = 1.0f / stepN;
    float acc = 0.0f;

    const unsigned int* P  = (const unsigned int*)volp;
    const __half*       Vh = (const __half*)volp;

    // incremental coordinate stepping: +64 samples per iteration
    float al0 = (float)(pstart + lane) * step;
    float x = fmaf(al0, vdx, vsx);
    float y = fmaf(al0, vdy, vsy);
    float z = fmaf(al0, vdz, vsz);
    float d64x = 64.0f * step * vdx;
    float d64y = 64.0f * step * vdy;
    float d64z = 64.0f * step * vdz;

    #pragma unroll 4
    for (int p = pstart + lane; p <= pend; p += 64) {
        float fx = floorf(x), fy = floorf(y), fz = floorf(z);
        int ix = (int)fx, iy = (int)fy, iz = (int)fz;
        float wx = x - fx, wy = y - fy, wz = z - fz;
        x += d64x; y += d64y; z += d64z;

        if (PACKED) {
            float2 p00, p01, p10, p11;   // (y, y+1) pairs at (x|x+1, z|z+1)
            bool interior = ((unsigned)ix < 255u) & ((unsigned)iy < 256u) &
                            ((unsigned)iz < 255u);
            if (interior) {
                int idx = (iz << 16) | (iy << 8) | ix;
                uint2v va, vb;
                __builtin_memcpy(&va, P + idx, 8);          // (x, x+1) @ z
                __builtin_memcpy(&vb, P + idx + 65536, 8);  // (x, x+1) @ z+1
                p00 = unpack_h2(va.x);
                p01 = unpack_h2(va.y);
                p10 = unpack_h2(vb.x);
                p11 = unpack_h2(vb.y);
            } else {
                p00 = fetchP(P, ix,     iy, iz);
                p01 = fetchP(P, ix + 1, iy, iz);
                p10 = fetchP(P, ix,     iy, iz + 1);
                p11 = fetchP(P, ix + 1, iy, iz + 1);
            }
            float c00 = p00.x + wy * (p00.y - p00.x);   // (x,   z)
            float c10 = p01.x + wy * (p01.y - p01.x);   // (x+1, z)
            float c01 = p10.x + wy * (p10.y - p10.x);   // (x,   z+1)
            float c11 = p11.x + wy * (p11.y - p11.x);   // (x+1, z+1)
            float c0  = c00 + wz * (c01 - c00);
            float c1  = c10 + wz * (c11 - c10);
            acc += c0 + wx * (c1 - c0);
        } else {
            float c000 = fetch_half(Vh, ix,     iy,     iz);
            float c100 = fetch_half(Vh, ix + 1, iy,     iz);
            float c010 = fetch_half(Vh, ix,     iy + 1, iz);
            float c110 = fetch_half(Vh, ix + 1, iy + 1, iz);
            float c001 = fetch_half(Vh, ix,     iy,     iz + 1);
            float c101 = fetch_half(Vh, ix + 1, iy,     iz + 1);
            float c011 = fetch_half(Vh, ix,     iy + 1, iz + 1);
            float c111 = fetch_half(Vh, ix + 1, iy + 1, iz + 1);
            float c00 = c000 + wz * (c001 - c000);
            float c01 = c010 + wz * (c011 - c010);
            float c10 = c100 + wz * (c101 - c100);
            float c11 = c110 + wz * (c111 - c110);
            float c0  = c00 + wy * (c01 - c00);
            float c1  = c10 + wy * (c11 - c10);
            acc += c0 + wx * (c1 - c0);
        }
    }

    #pragma unroll
    for (int off = 32; off > 0; off >>= 1)
        acc += __shfl_down(acc, off);

    if (lane == 0)
        out[ray] = acc * rl / (float)npts;
}

// ---------------------------------------------------------------------------
extern "C" void kernel_launch(void* const* d_in, const int* in_sizes, int n_in,
                              void* d_out, int out_size, void* d_ws, size_t ws_size,
                              hipStream_t stream)
{
    const float* dens   = (const float*)d_in[0];
    const float* source = (const float*)d_in[1];
    const float* target = (const float*)d_in[2];
    const float* affine = (const float*)d_in[3];
    const int*   npts   = (const int*)d_in[4];
    float* out = (float*)d_out;

    const int nvox  = in_sizes[0];          // 256^3
    const int nrays = in_sizes[1] / 3;      // B*N

    size_t packBytes = ((size_t)nvox * 4 + 255) & ~(size_t)255;
    size_t halfBytes = ((size_t)nvox * 2 + 255) & ~(size_t)255;
    size_t sortBytes = (size_t)(3 * NBUCKETS + nrays) * sizeof(int);

    const int ray_blocks = (nrays + 3) / 4;

    const bool packed = (ws_size >= packBytes + sortBytes);
    size_t volBytes = packed ? packBytes : halfBytes;

    int* hist   = (int*)((char*)d_ws + volBytes);
    int* offs   = hist + NBUCKETS;
    int* cursor = offs + NBUCKETS;
    int* perm   = cursor + NBUCKETS;
    const bool srt = (ws_size >= volBytes + sortBytes);
    int* permArg = srt ? perm : nullptr;

    if (srt) {
        zero_kernel<<<(3 * NBUCKETS + 255) / 256, 256, 0, stream>>>(hist, 3 * NBUCKETS);
        hist_kernel<<<(nrays + 255) / 256, 256, 0, stream>>>(target, hist, nrays);
        scan_kernel<<<1, NBUCKETS, 0, stream>>>(hist, offs);
        scatter_kernel<<<(nrays + 255) / 256, 256, 0, stream>>>(target, offs, cursor, perm, nrays);
    }

    if (packed) {
        unsigned int* P = (unsigned int*)d_ws;
        pack_kernel<<<2048, 256, 0, stream>>>(dens, P);
        drr_kernel<true><<<ray_blocks, 256, 0, stream>>>(
            P, source, target, affine, npts, permArg, out, nrays);
    } else {
        __half* vol = (__half*)d_ws;
        sigmoid_transpose_kernel<<<16384, 256, 0, stream>>>(dens, vol);
        drr_kernel<false><<<ray_blocks, 256, 0, stream>>>(
            vol, source, target, affine, npts, permArg, out, nrays);
    }
}

// Round 6
// 172.002 us; speedup vs baseline: 3.0816x; 1.1359x over previous
//
#include <hip/hip_runtime.h>
#include <hip/hip_fp16.h>

#define NB 64
#define NBUCKETS (NB * NB)   // 4096

typedef unsigned int uint2v __attribute__((ext_vector_type(2)));

__device__ __forceinline__ float sigm(float v)
{
    return 1.0f / (1.0f + __expf(0.3f - v));
}

__device__ __forceinline__ float2 unpack_h2(unsigned int w)
{
    __half2 h = *reinterpret_cast<__half2*>(&w);
    return make_float2(__low2float(h), __high2float(h));
}

// ---------------------------------------------------------------------------
// Phase 1a: sigmoid + transpose + y-pair pack, with y-carry.
// Input  dens[x][y][z] fp32 (z fastest). Output P[z][y][x] uint (x fastest),
// P = half2( sig(v[z][y][x]), sig(v[z][y+1][x]) ), y+1==256 -> 0.
// Block: one (32x,32z) tile for 8 consecutive y planes, carrying plane y+1.
// ---------------------------------------------------------------------------
__global__ __launch_bounds__(256) void pack_kernel(
    const float* __restrict__ dens, unsigned int* __restrict__ P)
{
    __shared__ float tile[32][33];
    int bid = blockIdx.x;
    int y0 = (bid & 31) * 8;
    int xt = ((bid >> 5) & 7) * 32;
    int zt = (bid >> 8) * 32;
    int tz = threadIdx.x & 31;
    int tr = threadIdx.x >> 5;              // 0..7

    float prev[4];
    int ytop = y0 + 8;
    if (ytop < 256) {
        #pragma unroll
        for (int i = 0; i < 4; ++i) {
            int xr = tr + 8 * i;
            tile[xr][tz] = sigm(dens[(size_t)(xt + xr) * 65536 +
                                     (size_t)ytop * 256 + (zt + tz)]);
        }
        __syncthreads();
        #pragma unroll
        for (int i = 0; i < 4; ++i)
            prev[i] = tile[tz][tr + 8 * i];
        __syncthreads();
    } else {
        #pragma unroll
        for (int i = 0; i < 4; ++i) prev[i] = 0.0f;
    }

    for (int yy = 7; yy >= 0; --yy) {
        int y = y0 + yy;
        #pragma unroll
        for (int i = 0; i < 4; ++i) {
            int xr = tr + 8 * i;
            tile[xr][tz] = sigm(dens[(size_t)(xt + xr) * 65536 +
                                     (size_t)y * 256 + (zt + tz)]);
        }
        __syncthreads();
        #pragma unroll
        for (int i = 0; i < 4; ++i) {
            int zr = tr + 8 * i;
            float cur = tile[tz][zr];
            __half2 h = __floats2half2_rn(cur, prev[i]);
            P[((zt + zr) << 16) | (y << 8) | (xt + tz)] =
                *reinterpret_cast<unsigned int*>(&h);
            prev[i] = cur;
        }
        __syncthreads();
    }
}

// ---------------------------------------------------------------------------
// Ray bucketing: Morton-interleaved 64x64 grid over detector (ty, tz)
// ---------------------------------------------------------------------------
__device__ __forceinline__ int ray_bucket(const float* __restrict__ target, int r)
{
    float ty = target[3 * r + 1];
    float tz = target[3 * r + 2];
    int bu = (int)((ty + 10.0f) * (NB / 260.0f));
    int bv = (int)((tz + 10.0f) * (NB / 260.0f));
    bu = min(max(bu, 0), NB - 1);
    bv = min(max(bv, 0), NB - 1);
    int m = 0;
    #pragma unroll
    for (int b = 0; b < 6; ++b)
        m |= (((bu >> b) & 1) << (2 * b)) | (((bv >> b) & 1) << (2 * b + 1));
    return m;
}

__global__ __launch_bounds__(256) void zero_kernel(int* __restrict__ p, int n)
{
    int i = blockIdx.x * 256 + threadIdx.x;
    if (i < n) p[i] = 0;
}

__global__ __launch_bounds__(256) void hist_kernel(
    const float* __restrict__ target, int* __restrict__ hist, int nrays)
{
    int r = blockIdx.x * 256 + threadIdx.x;
    if (r < nrays) atomicAdd(&hist[ray_bucket(target, r)], 1);
}

// single block, 256 threads, 16 buckets each: exclusive scan + cursor zero
__global__ __launch_bounds__(256) void scan_kernel(
    const int* __restrict__ hist, int* __restrict__ offs, int* __restrict__ cursor)
{
    __shared__ int part[256];
    int t = threadIdx.x;
    int v[16];
    int s = 0;
    #pragma unroll
    for (int i = 0; i < 16; ++i) {
        v[i] = hist[t * 16 + i];
        s += v[i];
    }
    part[t] = s;
    __syncthreads();
    // Hillis-Steele inclusive scan on 256 partials
    for (int d = 1; d < 256; d <<= 1) {
        int add = (t >= d) ? part[t - d] : 0;
        __syncthreads();
        part[t] += add;
        __syncthreads();
    }
    int base = part[t] - s;   // exclusive prefix of this thread's chunk
    #pragma unroll
    for (int i = 0; i < 16; ++i) {
        offs[t * 16 + i] = base;
        base += v[i];
        cursor[t * 16 + i] = 0;
    }
}

__global__ __launch_bounds__(256) void scatter_kernel(
    const float* __restrict__ target, const int* __restrict__ offs,
    int* __restrict__ cursor, int* __restrict__ perm, int nrays)
{
    int r = blockIdx.x * 256 + threadIdx.x;
    if (r >= nrays) return;
    int bkt = ray_bucket(target, r);
    int pos = offs[bkt] + atomicAdd(&cursor[bkt], 1);
    perm[pos] = r;
}

// ---------------------------------------------------------------------------
// Checked packed fetch (boundary path)
// ---------------------------------------------------------------------------
__device__ __forceinline__ float2 fetchP(
    const unsigned int* __restrict__ P, int x, int y, int z)
{
    if ((unsigned)x < 256u && (unsigned)z < 256u) {
        if ((unsigned)y < 256u)
            return unpack_h2(P[(z << 16) | (y << 8) | x]);
        if (y == -1) {
            float2 v = unpack_h2(P[(z << 16) | x]);
            return make_float2(0.0f, v.x);
        }
    }
    return make_float2(0.0f, 0.0f);
}

// ---------------------------------------------------------------------------
// Phase 2: ray-packeted — each wave handles 4 neighboring rays x 16 samples.
// lane l: ray sub-id = l>>4, sample phase = l&15. Segmented 16-lane reduce.
// ---------------------------------------------------------------------------
__global__ __launch_bounds__(256) void drr_kernel(
    const unsigned int* __restrict__ P,
    const float*  __restrict__ source,
    const float*  __restrict__ target,
    const float*  __restrict__ affine,
    const int*    __restrict__ npts_ptr,
    const int*    __restrict__ perm,
    float*        __restrict__ out,
    int nrays)
{
    const int lane  = threadIdx.x & 63;
    const int sub   = lane >> 4;            // ray within wave (0..3)
    const int phase = lane & 15;            // sample phase (0..15)
    const int wave  = threadIdx.x >> 6;     // wave within block (0..3)
    int slot = blockIdx.x * 16 + wave * 4 + sub;
    bool valid = (slot < nrays);
    if (slot >= nrays) slot = nrays - 1;
    const int ray = perm ? perm[slot] : slot;
    const int npts = *npts_ptr;

    // inverse affine (last row [0,0,0,1])
    float a00 = affine[0], a01 = affine[1], a02 = affine[2],  b0 = affine[3];
    float a10 = affine[4], a11 = affine[5], a12 = affine[6],  b1 = affine[7];
    float a20 = affine[8], a21 = affine[9], a22 = affine[10], b2 = affine[11];
    float det = a00 * (a11 * a22 - a12 * a21)
              - a01 * (a10 * a22 - a12 * a20)
              + a02 * (a10 * a21 - a11 * a20);
    float rdet = 1.0f / det;
    float i00 =  (a11 * a22 - a12 * a21) * rdet;
    float i01 = -(a01 * a22 - a02 * a21) * rdet;
    float i02 =  (a01 * a12 - a02 * a11) * rdet;
    float i10 = -(a10 * a22 - a12 * a20) * rdet;
    float i11 =  (a00 * a22 - a02 * a20) * rdet;
    float i12 = -(a00 * a12 - a02 * a10) * rdet;
    float i20 =  (a10 * a21 - a11 * a20) * rdet;
    float i21 = -(a00 * a21 - a01 * a20) * rdet;
    float i22 =  (a00 * a11 - a01 * a10) * rdet;
    float it0 = -(i00 * b0 + i01 * b1 + i02 * b2);
    float it1 = -(i10 * b0 + i11 * b1 + i12 * b2);
    float it2 = -(i20 * b0 + i21 * b1 + i22 * b2);

    float sx = source[3 * ray + 0], sy = source[3 * ray + 1], sz = source[3 * ray + 2];
    float tx = target[3 * ray + 0], ty = target[3 * ray + 1], tz = target[3 * ray + 2];
    float dwx = tx - sx, dwy = ty - sy, dwz = tz - sz;
    float rl = sqrtf(dwx * dwx + dwy * dwy + dwz * dwz);

    float vsx = i00 * sx + i01 * sy + i02 * sz + it0;
    float vsy = i10 * sx + i11 * sy + i12 * sz + it1;
    float vsz = i20 * sx + i21 * sy + i22 * sz + it2;
    float vtx = i00 * tx + i01 * ty + i02 * tz + it0;
    float vty = i10 * tx + i11 * ty + i12 * tz + it1;
    float vtz = i20 * tx + i21 * ty + i22 * tz + it2;
    float vdx = vtx - vsx, vdy = vty - vsy, vdz = vtz - vsz;

    // clip to alpha range where a sample can touch an in-bounds corner
    float lo = 0.0f, hi = 1.0f;
    {
        float s3v[3] = {vsx, vsy, vsz};
        float d3v[3] = {vdx, vdy, vdz};
        #pragma unroll
        for (int k = 0; k < 3; ++k) {
            if (fabsf(d3v[k]) > 1e-8f) {
                float a = (-1.0f - s3v[k]) / d3v[k];
                float b = (256.0f - s3v[k]) / d3v[k];
                lo = fmaxf(lo, fminf(a, b));
                hi = fminf(hi, fmaxf(a, b));
            } else if (s3v[k] <= -1.0f || s3v[k] >= 256.0f) {
                lo = 1.0f; hi = 0.0f;
            }
        }
    }
    const float stepN = (float)(npts > 1 ? npts - 1 : 1);
    int pstart = max(0, (int)floorf(lo * stepN) - 1);
    int pend   = min(npts - 1, (int)ceilf(hi * stepN) + 1);

    const float step = 1.0f / stepN;
    float acc = 0.0f;

    // incremental stepping: +16 samples per iteration
    float al0 = (float)(pstart + phase) * step;
    float x = fmaf(al0, vdx, vsx);
    float y = fmaf(al0, vdy, vsy);
    float z = fmaf(al0, vdz, vsz);
    float d16x = 16.0f * step * vdx;
    float d16y = 16.0f * step * vdy;
    float d16z = 16.0f * step * vdz;

    #pragma unroll 4
    for (int p = pstart + phase; p <= pend; p += 16) {
        float fx = floorf(x), fy = floorf(y), fz = floorf(z);
        int ix = (int)fx, iy = (int)fy, iz = (int)fz;
        float wx = x - fx, wy = y - fy, wz = z - fz;
        x += d16x; y += d16y; z += d16z;

        float2 p00, p01, p10, p11;   // (y, y+1) pairs at (x|x+1, z|z+1)
        bool interior = ((unsigned)ix < 255u) & ((unsigned)iy < 256u) &
                        ((unsigned)iz < 255u);
        if (interior) {
            int idx = (iz << 16) | (iy << 8) | ix;
            uint2v va, vb;
            __builtin_memcpy(&va, P + idx, 8);          // (x, x+1) @ z
            __builtin_memcpy(&vb, P + idx + 65536, 8);  // (x, x+1) @ z+1
            p00 = unpack_h2(va.x);
            p01 = unpack_h2(va.y);
            p10 = unpack_h2(vb.x);
            p11 = unpack_h2(vb.y);
        } else {
            p00 = fetchP(P, ix,     iy, iz);
            p01 = fetchP(P, ix + 1, iy, iz);
            p10 = fetchP(P, ix,     iy, iz + 1);
            p11 = fetchP(P, ix + 1, iy, iz + 1);
        }
        float c00 = p00.x + wy * (p00.y - p00.x);   // (x,   z)
        float c10 = p01.x + wy * (p01.y - p01.x);   // (x+1, z)
        float c01 = p10.x + wy * (p10.y - p10.x);   // (x,   z+1)
        float c11 = p11.x + wy * (p11.y - p11.x);   // (x+1, z+1)
        float c0  = c00 + wz * (c01 - c00);
        float c1  = c10 + wz * (c11 - c10);
        acc += c0 + wx * (c1 - c0);
    }

    // segmented 16-lane reduction (4 rays per wave)
    #pragma unroll
    for (int off = 8; off > 0; off >>= 1)
        acc += __shfl_down(acc, off, 16);

    if (phase == 0 && valid)
        out[ray] = acc * rl / (float)npts;
}

// ---------------------------------------------------------------------------
extern "C" void kernel_launch(void* const* d_in, const int* in_sizes, int n_in,
                              void* d_out, int out_size, void* d_ws, size_t ws_size,
                              hipStream_t stream)
{
    const float* dens   = (const float*)d_in[0];
    const float* source = (const float*)d_in[1];
    const float* target = (const float*)d_in[2];
    const float* affine = (const float*)d_in[3];
    const int*   npts   = (const int*)d_in[4];
    float* out = (float*)d_out;

    const int nvox  = in_sizes[0];          // 256^3
    const int nrays = in_sizes[1] / 3;      // B*N

    size_t packBytes = ((size_t)nvox * 4 + 255) & ~(size_t)255;
    size_t sortBytes = (size_t)(3 * NBUCKETS + nrays) * sizeof(int);

    // 16 rays per block (4 waves x 4 rays)
    const int ray_blocks = (nrays + 15) / 16;

    unsigned int* P = (unsigned int*)d_ws;
    int* hist   = (int*)((char*)d_ws + packBytes);
    int* offs   = hist + NBUCKETS;
    int* cursor = offs + NBUCKETS;
    int* perm   = cursor + NBUCKETS;
    const bool srt = (ws_size >= packBytes + sortBytes);
    int* permArg = srt ? perm : nullptr;

    if (srt) {
        zero_kernel<<<(NBUCKETS + 255) / 256, 256, 0, stream>>>(hist, NBUCKETS);
        hist_kernel<<<(nrays + 255) / 256, 256, 0, stream>>>(target, hist, nrays);
        scan_kernel<<<1, 256, 0, stream>>>(hist, offs, cursor);
        scatter_kernel<<<(nrays + 255) / 256, 256, 0, stream>>>(target, offs, cursor, perm, nrays);
    }

    pack_kernel<<<2048, 256, 0, stream>>>(dens, P);
    drr_kernel<<<ray_blocks, 256, 0, stream>>>(
        P, source, target, affine, npts, permArg, out, nrays);
}